// Round 1
// baseline (701.932 us; speedup 1.0000x reference)
//
#include <hip/hip_runtime.h>

#define FEPS 1e-12f

__device__ __forceinline__ void top3_insert(float val, int idx,
                                            float& v0, float& v1, float& v2,
                                            int& i0, int& i1, int& i2) {
    if (val > v0)      { v2 = v1; i2 = i1; v1 = v0; i1 = i0; v0 = val; i0 = idx; }
    else if (val > v1) { v2 = v1; i2 = i1; v1 = val; i1 = idx; }
    else if (val > v2) { v2 = val; i2 = idx; }
}

// Split-K GEMV, float4 columns: out[j..j+3] += sum_{i in chunk} f(v[i]) * W[i,j..j+3]
// W row-major (R x C). grid = (C/1024, R/CHUNK), block = 256. out pre-zeroed.
// CHUNK compile-time -> full unroll, all loads issued before accumulation chain.
template<int RELU, int CHUNK>
__global__ __launch_bounds__(256)
void gemv_atomic4(const float* __restrict__ v,
                  const float* __restrict__ W,
                  const float* __restrict__ bias,
                  float* __restrict__ out,
                  int C) {
    int j = (blockIdx.x * 256 + threadIdx.x) * 4;
    int i0 = blockIdx.y * CHUNK;
    float4 acc = make_float4(0.f, 0.f, 0.f, 0.f);
    #pragma unroll
    for (int u = 0; u < CHUNK; ++u) {
        int i = i0 + u;
        float vi = v[i];
        if (RELU) vi = fmaxf(vi, 0.f);
        float4 w = *(const float4*)(W + (size_t)i * C + j);
        acc.x = fmaf(vi, w.x, acc.x);
        acc.y = fmaf(vi, w.y, acc.y);
        acc.z = fmaf(vi, w.z, acc.z);
        acc.w = fmaf(vi, w.w, acc.w);
    }
    if (blockIdx.y == 0) {
        float4 b = *(const float4*)(bias + j);
        acc.x += b.x; acc.y += b.y; acc.z += b.z; acc.w += b.w;
    }
    atomicAdd(&out[j + 0], acc.x);
    atomicAdd(&out[j + 1], acc.y);
    atomicAdd(&out[j + 2], acc.z);
    atomicAdd(&out[j + 3], acc.w);
}

// Each block: 64 key rows (wave w -> rows base+w*16 .. +15). Computes
// weighted[m] = (q.k_m) * imp[m] / max(||k_m||,eps)  (÷||q|| deferred — positive
// scalar, order-preserving), emits block top-3, and the LAST finishing block
// (device-scope ticket) does the global top-3 + softmax + values gather +
// zeroes `out` for the following Wout GEMV.
__global__ __launch_bounds__(256)
void sims_top3_fused(const float* __restrict__ q,
                     const float* __restrict__ keys,
                     const float* __restrict__ imp,
                     const float* __restrict__ values,
                     float* __restrict__ cand_val,
                     int* __restrict__ cand_idx,
                     unsigned* __restrict__ ctr,
                     float* __restrict__ retr,     // = comb + 2048
                     float* __restrict__ out) {    // zeroed here (2048)
    __shared__ float qs[1024];
    __shared__ float wv[4 * 3];
    __shared__ int   wi[4 * 3];
    __shared__ float s_red[4];
    __shared__ float s_attn[3];
    __shared__ int   s_idx[3];
    __shared__ int   s_last;
    int t = threadIdx.x;
    #pragma unroll
    for (int p = 0; p < 4; ++p) qs[t + 256 * p] = q[t + 256 * p];
    __syncthreads();
    int wave = t >> 6, lane = t & 63;
    const float4* q4 = (const float4*)qs;
    float4 qv[4];
    #pragma unroll
    for (int p = 0; p < 4; ++p) qv[p] = q4[lane + 64 * p];

    float v0 = -INFINITY, v1 = -INFINITY, v2 = -INFINITY;
    int   i0 = -1, i1 = -1, i2 = -1;
    int mbase = blockIdx.x * 64 + wave * 16;
    // 4-row groups: 16 independent dwordx4 loads in flight before any shuffle.
    for (int r = 0; r < 16; r += 4) {
        float dot[4] = {0.f, 0.f, 0.f, 0.f};
        float sq[4]  = {0.f, 0.f, 0.f, 0.f};
        #pragma unroll
        for (int u = 0; u < 4; ++u) {
            const float4* krow = (const float4*)(keys + (size_t)(mbase + r + u) * 1024);
            #pragma unroll
            for (int p = 0; p < 4; ++p) {
                float4 k = krow[lane + 64 * p];
                dot[u] = fmaf(k.x, qv[p].x, dot[u]);
                dot[u] = fmaf(k.y, qv[p].y, dot[u]);
                dot[u] = fmaf(k.z, qv[p].z, dot[u]);
                dot[u] = fmaf(k.w, qv[p].w, dot[u]);
                sq[u]  = fmaf(k.x, k.x, sq[u]);
                sq[u]  = fmaf(k.y, k.y, sq[u]);
                sq[u]  = fmaf(k.z, k.z, sq[u]);
                sq[u]  = fmaf(k.w, k.w, sq[u]);
            }
        }
        #pragma unroll
        for (int off = 32; off; off >>= 1) {
            #pragma unroll
            for (int u = 0; u < 4; ++u) {
                dot[u] += __shfl_down(dot[u], off);
                sq[u]  += __shfl_down(sq[u], off);
            }
        }
        if (lane == 0) {
            #pragma unroll
            for (int u = 0; u < 4; ++u) {
                int m = mbase + r + u;
                float val = dot[u] * imp[m] / fmaxf(sqrtf(sq[u]), FEPS);
                top3_insert(val, m, v0, v1, v2, i0, i1, i2);
            }
        }
    }
    if (lane == 0) {
        wv[wave * 3 + 0] = v0; wv[wave * 3 + 1] = v1; wv[wave * 3 + 2] = v2;
        wi[wave * 3 + 0] = i0; wi[wave * 3 + 1] = i1; wi[wave * 3 + 2] = i2;
    }
    __syncthreads();
    if (t == 0) {
        float a0 = -INFINITY, a1 = -INFINITY, a2 = -INFINITY;
        int   b0 = -1, b1 = -1, b2 = -1;
        for (int e = 0; e < 12; ++e)
            top3_insert(wv[e], wi[e], a0, a1, a2, b0, b1, b2);
        int base = blockIdx.x * 3;
        __hip_atomic_store(&cand_val[base + 0], a0, __ATOMIC_RELAXED, __HIP_MEMORY_SCOPE_AGENT);
        __hip_atomic_store(&cand_val[base + 1], a1, __ATOMIC_RELAXED, __HIP_MEMORY_SCOPE_AGENT);
        __hip_atomic_store(&cand_val[base + 2], a2, __ATOMIC_RELAXED, __HIP_MEMORY_SCOPE_AGENT);
        __hip_atomic_store(&cand_idx[base + 0], b0, __ATOMIC_RELAXED, __HIP_MEMORY_SCOPE_AGENT);
        __hip_atomic_store(&cand_idx[base + 1], b1, __ATOMIC_RELAXED, __HIP_MEMORY_SCOPE_AGENT);
        __hip_atomic_store(&cand_idx[base + 2], b2, __ATOMIC_RELAXED, __HIP_MEMORY_SCOPE_AGENT);
        __threadfence();
        unsigned tk = __hip_atomic_fetch_add(ctr, 1u, __ATOMIC_ACQ_REL, __HIP_MEMORY_SCOPE_AGENT);
        s_last = (tk == gridDim.x - 1) ? 1 : 0;
    }
    __syncthreads();
    if (!s_last) return;

    // ---------------- last block: global finalize ----------------
    __threadfence();
    // ||q|| from qs (already staged in LDS)
    float pq = 0.f;
    #pragma unroll
    for (int p = 0; p < 4; ++p) { float x = qs[t + 256 * p]; pq = fmaf(x, x, pq); }
    #pragma unroll
    for (int off = 32; off; off >>= 1) pq += __shfl_down(pq, off);

    // per-thread top-3 over 12 candidates each (coalesced stride-256)
    float c0 = -INFINITY, c1 = -INFINITY, c2 = -INFINITY;
    int   d0 = -1, d1 = -1, d2 = -1;
    #pragma unroll
    for (int kk = 0; kk < 12; ++kk) {
        int c = t + (kk << 8);
        float val = __hip_atomic_load(&cand_val[c], __ATOMIC_RELAXED, __HIP_MEMORY_SCOPE_AGENT);
        int   idx = __hip_atomic_load(&cand_idx[c], __ATOMIC_RELAXED, __HIP_MEMORY_SCOPE_AGENT);
        top3_insert(val, idx, c0, c1, c2, d0, d1, d2);
    }
    // wave-level merge of top-3 triples
    #pragma unroll
    for (int off = 32; off; off >>= 1) {
        float u0 = __shfl_down(c0, off), u1 = __shfl_down(c1, off), u2 = __shfl_down(c2, off);
        int   j0 = __shfl_down(d0, off), j1 = __shfl_down(d1, off), j2 = __shfl_down(d2, off);
        top3_insert(u0, j0, c0, c1, c2, d0, d1, d2);
        top3_insert(u1, j1, c0, c1, c2, d0, d1, d2);
        top3_insert(u2, j2, c0, c1, c2, d0, d1, d2);
    }
    if (lane == 0) {
        wv[wave * 3 + 0] = c0; wv[wave * 3 + 1] = c1; wv[wave * 3 + 2] = c2;
        wi[wave * 3 + 0] = d0; wi[wave * 3 + 1] = d1; wi[wave * 3 + 2] = d2;
        s_red[wave] = pq;
    }
    __syncthreads();
    if (t == 0) {
        float a0 = -INFINITY, a1 = -INFINITY, a2 = -INFINITY;
        int   b0 = -1, b1 = -1, b2 = -1;
        for (int e = 0; e < 12; ++e)
            top3_insert(wv[e], wi[e], a0, a1, a2, b0, b1, b2);
        float qden = fmaxf(sqrtf(s_red[0] + s_red[1] + s_red[2] + s_red[3]), FEPS);
        float tv0 = a0 / qden, tv1 = a1 / qden, tv2 = a2 / qden;
        float mx = fmaxf(tv0, fmaxf(tv1, tv2));
        float e0 = expf(tv0 - mx), e1 = expf(tv1 - mx), e2 = expf(tv2 - mx);
        float sum = e0 + e1 + e2;
        s_attn[0] = e0 / sum; s_attn[1] = e1 / sum; s_attn[2] = e2 / sum;
        s_idx[0] = b0; s_idx[1] = b1; s_idx[2] = b2;
    }
    __syncthreads();

    // retrieved[1024] = attn @ values[top_idx]
    #pragma unroll
    for (int p = 0; p < 4; ++p) {
        int col = t + 256 * p;
        float r = s_attn[0] * values[(size_t)s_idx[0] * 1024 + col]
                + s_attn[1] * values[(size_t)s_idx[1] * 1024 + col]
                + s_attn[2] * values[(size_t)s_idx[2] * 1024 + col];
        retr[col] = r;
    }
    // zero out[2048] for the following atomic Wout GEMV (replaces host memset)
    #pragma unroll
    for (int p = 0; p < 8; ++p) out[t + 256 * p] = 0.0f;
}

extern "C" void kernel_launch(void* const* d_in, const int* in_sizes, int n_in,
                              void* d_out, int out_size, void* d_ws, size_t ws_size,
                              hipStream_t stream) {
    const float* x      = (const float*)d_in[0];
    const float* W1     = (const float*)d_in[1];
    const float* b1     = (const float*)d_in[2];
    const float* W2     = (const float*)d_in[3];
    const float* b2     = (const float*)d_in[4];
    const float* Wq     = (const float*)d_in[5];
    const float* bq     = (const float*)d_in[6];
    const float* Wout   = (const float*)d_in[7];
    const float* bout   = (const float*)d_in[8];
    const float* keys   = (const float*)d_in[9];
    const float* values = (const float*)d_in[10];
    const float* imp    = (const float*)d_in[11];
    float* out = (float*)d_out;
    float* ws  = (float*)d_ws;

    // ws layout (floats):
    // [0,2048)       h1
    // [2048,5120)    comb = last_hidden (2048) | retrieved (1024)
    // [5120,6144)    q
    // [6144]         done-counter (unsigned)
    // [6160,9232)    cand_val (3072)
    // [9232,12304)   cand_idx (3072 ints)
    float*    h1       = ws;
    float*    comb     = ws + 2048;
    float*    retr     = ws + 4096;
    float*    q        = ws + 5120;
    unsigned* ctr      = (unsigned*)(ws + 6144);
    float*    cand_val = ws + 6160;
    int*      cand_idx = (int*)(ws + 9232);

    const float* xlast = x + (size_t)(4096 - 1) * 2048;  // only last position matters

    // zero atomic accumulators (h1, comb, q) + counter. d_out zeroed in-kernel.
    hipMemsetAsync(d_ws, 0, 6160 * sizeof(float), stream);

    // h1 = xlast @ W1 + b1                       (16 MB)
    gemv_atomic4<0, 8><<<dim3(2, 256), 256, 0, stream>>>(xlast, W1, b1, h1, 2048);
    // last_hidden = relu(h1) @ W2 + b2           (16 MB)
    gemv_atomic4<1, 8><<<dim3(2, 256), 256, 0, stream>>>(h1, W2, b2, comb, 2048);
    // q = last_hidden @ Wq + bq                  (8 MB)
    gemv_atomic4<0, 8><<<dim3(1, 256), 256, 0, stream>>>(comb, Wq, bq, q, 1024);
    // sims + per-block top-3 over 65536 keys (256 MB — dominant) + fused
    // global top-3 / softmax / values-gather / out-zeroing in last block
    sims_top3_fused<<<1024, 256, 0, stream>>>(q, keys, imp, values,
                                              cand_val, cand_idx, ctr, retr, out);
    // out = comb @ Wout + bout                   (24 MB)
    gemv_atomic4<0, 12><<<dim3(2, 256), 256, 0, stream>>>(comb, Wout, bout, out, 2048);
}